// Round 4
// baseline (17031.554 us; speedup 1.0000x reference)
//
#include <hip/hip_runtime.h>
#include <math.h>

// ---------------------------------------------------------------------------
// CDDD decoder: 3-layer GRU (512/1024/2048) greedy autoregressive decode.
// B=64 (lane = batch), 64 steps, fp32, token-exact target.
//
// v4: weights are wave-uniform -> load via s_load_dwordx8 into SGPRs (scalar
// memory path, no TA/VMEM slot, no VGPRs). v_fma_f32 takes the SGPR operand
// directly. Activations stay lane=batch coalesced float4 in "T4" layout:
//   buf[(k4*64+b)*4+c] == value[b][k4*4+c]
// Ping-pong software pipeline, static indexing; consumers ordered after
// s_waitcnt via tied "+s" asm operands.
// ---------------------------------------------------------------------------

#define BATCH 64

typedef float v8f __attribute__((ext_vector_type(8)));

__device__ __forceinline__ v8f sload8(const float* p) {
    v8f r;
    asm volatile("s_load_dwordx8 %0, %1, 0x0" : "=s"(r) : "s"(p));
    return r;
}

#define SWAIT3(a, b, c) \
    asm volatile("s_waitcnt lgkmcnt(0)" : "+s"(a), "+s"(b), "+s"(c))

__device__ __forceinline__ void fma8(float& acc, const v8f w,
                                     const float4 a, const float4 b) {
    acc = fmaf(w[0], a.x, acc);
    acc = fmaf(w[1], a.y, acc);
    acc = fmaf(w[2], a.z, acc);
    acc = fmaf(w[3], a.w, acc);
    acc = fmaf(w[4], b.x, acc);
    acc = fmaf(w[5], b.y, acc);
    acc = fmaf(w[6], b.z, acc);
    acc = fmaf(w[7], b.w, acc);
}

__device__ __forceinline__ float sigmoid_f(float x) {
    return 1.0f / (1.0f + expf(-x));
}

// act load: EMB mode -> actbase is a per-lane row pointer (emb + tok*32),
// T4 mode -> actbase is the T4 buffer, quad index q*64+b.
template<bool EMB>
__device__ __forceinline__ float4 lact(const float* actbase, int q, int b) {
    if (EMB) return ((const float4*)actbase)[q];
    else     return ((const float4*)actbase)[q * 64 + b];
}

// One GEMV phase over nchunks chunks of 8 K-elements (nchunks even, >= 2).
// pr/pz/pn: wave-uniform weight row pointers (gate r/z/n) at the phase start.
// Accumulates into accR/accZ/accN.
template<bool EMB>
__device__ __forceinline__ void gemv_phase(
    const float* pr, const float* pz, const float* pn,
    const float* actbase, int qbase, int b, int nchunks,
    float& accR, float& accZ, float& accN)
{
    v8f wa0 = sload8(pr);
    v8f wa1 = sload8(pz);
    v8f wa2 = sload8(pn);
    float4 aa0 = lact<EMB>(actbase, qbase + 0, b);
    float4 aa1 = lact<EMB>(actbase, qbase + 1, b);

    int i = 0;
    for (; i + 2 < nchunks; i += 2) {
        v8f wb0 = sload8(pr + 8 * (i + 1));
        v8f wb1 = sload8(pz + 8 * (i + 1));
        v8f wb2 = sload8(pn + 8 * (i + 1));
        float4 ba0 = lact<EMB>(actbase, qbase + 2 * (i + 1), b);
        float4 ba1 = lact<EMB>(actbase, qbase + 2 * (i + 1) + 1, b);
        SWAIT3(wa0, wa1, wa2);
        fma8(accR, wa0, aa0, aa1);
        fma8(accZ, wa1, aa0, aa1);
        fma8(accN, wa2, aa0, aa1);

        wa0 = sload8(pr + 8 * (i + 2));
        wa1 = sload8(pz + 8 * (i + 2));
        wa2 = sload8(pn + 8 * (i + 2));
        aa0 = lact<EMB>(actbase, qbase + 2 * (i + 2), b);
        aa1 = lact<EMB>(actbase, qbase + 2 * (i + 2) + 1, b);
        SWAIT3(wb0, wb1, wb2);
        fma8(accR, wb0, ba0, ba1);
        fma8(accZ, wb1, ba0, ba1);
        fma8(accN, wb2, ba0, ba1);
    }
    // tail: chunks i and i+1
    {
        v8f wb0 = sload8(pr + 8 * (i + 1));
        v8f wb1 = sload8(pz + 8 * (i + 1));
        v8f wb2 = sload8(pn + 8 * (i + 1));
        float4 ba0 = lact<EMB>(actbase, qbase + 2 * (i + 1), b);
        float4 ba1 = lact<EMB>(actbase, qbase + 2 * (i + 1) + 1, b);
        SWAIT3(wa0, wa1, wa2);
        fma8(accR, wa0, aa0, aa1);
        fma8(accZ, wa1, aa0, aa1);
        fma8(accN, wa2, aa0, aa1);
        SWAIT3(wb0, wb1, wb2);
        fma8(accR, wb0, ba0, ba1);
        fma8(accZ, wb1, ba0, ba1);
        fma8(accN, wb2, ba0, ba1);
    }
}

// Transpose z [64,512] -> zT4, and init dec[] with start token.
__global__ __launch_bounds__(256) void init_misc_kernel(
    const float* __restrict__ z, float* __restrict__ zT4,
    int* __restrict__ dec, const int* __restrict__ start_tok)
{
    int tid = blockIdx.x * 256 + threadIdx.x;   // 8192 threads: (b, k4)
    int b  = tid >> 7;
    int k4 = tid & 127;
    float4 v = ((const float4*)z)[b * 128 + k4];
    ((float4*)zT4)[k4 * 64 + b] = v;
    if (tid < BATCH) dec[tid] = start_tok[0];
}

// init_states = z @ fc_init_w.T + fc_init_b ; split into h0/h1/h2 (T4 layout).
__global__ __launch_bounds__(256) void init_h_kernel(
    const float* __restrict__ zT4, const float* __restrict__ w,
    const float* __restrict__ bias,
    float* __restrict__ h0, float* __restrict__ h1, float* __restrict__ h2)
{
    const int wave = threadIdx.x >> 6;
    const int b    = threadIdx.x & 63;
    const int r    = blockIdx.x * 4 + wave;      // 0..3583
    const float4* w4 = (const float4*)(w + (size_t)r * 512);
    const float4* z4 = (const float4*)zT4;
    float acc = 0.f;
    #pragma unroll 8
    for (int k = 0; k < 128; ++k) {
        float4 wv = w4[k];
        float4 zv = z4[k * 64 + b];
        acc = fmaf(wv.x, zv.x, acc);
        acc = fmaf(wv.y, zv.y, acc);
        acc = fmaf(wv.z, zv.z, acc);
        acc = fmaf(wv.w, zv.w, acc);
    }
    acc += bias[r];
    float* dst; int j;
    if (r < 512)       { dst = h0; j = r; }
    else if (r < 1536) { dst = h1; j = r - 512; }
    else               { dst = h2; j = r - 1536; }
    dst[(((j >> 2) * 64 + b) << 2) + (j & 3)] = acc;
}

// GRU layer step, v4. Block = COLS*KSPLIT waves; wave (col,kh) computes the
// partial sums of column j = blockIdx*COLS+col over K-range kh.
template<int IN, int H, int COLS, int KSPLIT, bool L0>
__global__ __launch_bounds__(COLS * KSPLIT * 64) void gru4_kernel(
    const float* __restrict__ xT4,
    const float* __restrict__ emb, const int* __restrict__ dec,
    const float* __restrict__ hT4_in, float* __restrict__ hT4_out,
    const float* __restrict__ w_ih, const float* __restrict__ w_hh,
    const float* __restrict__ b_ih, const float* __restrict__ b_hh)
{
    constexpr int KT = IN + H;
    constexpr int KW = KT / KSPLIT;   // K elems per wave (multiple of 8)

    const int tid  = threadIdx.x;
    const int wave = tid >> 6;
    const int b    = tid & 63;
    const int col  = wave % COLS;
    const int kh   = wave / COLS;
    const uint32_t ju  = __builtin_amdgcn_readfirstlane(
                            (uint32_t)(blockIdx.x * COLS + col));
    const uint32_t khu = __builtin_amdgcn_readfirstlane((uint32_t)kh);

    const int e0 = (int)khu * KW;
    const int e1 = e0 + KW;

    float accR = 0.f, accZ = 0.f, accNX = 0.f, accNH = 0.f;

    // ---- x phase: concat-K range [e0, min(e1, IN)) ----
    const int xs1 = (e1 < IN) ? e1 : IN;
    if (e0 < xs1) {
        const int n = (xs1 - e0) / 8;
        const float* pr = w_ih + (size_t)ju * IN + e0;
        const float* pz = w_ih + ((size_t)ju + H) * IN + e0;
        const float* pn = w_ih + ((size_t)ju + 2 * H) * IN + e0;
        if (L0) {
            const int tok = dec[b];
            gemv_phase<true>(pr, pz, pn, emb + tok * 32 + 0, e0 / 4, b, n,
                             accR, accZ, accNX);
        } else {
            gemv_phase<false>(pr, pz, pn, xT4, e0 / 4, b, n,
                              accR, accZ, accNX);
        }
    }

    // ---- h phase: concat-K range [max(e0, IN), e1), k' = k - IN ----
    const int hs0 = (e0 > IN) ? e0 : IN;
    if (hs0 < e1) {
        const int k0 = hs0 - IN;
        const int n = (e1 - hs0) / 8;
        const float* pr = w_hh + (size_t)ju * H + k0;
        const float* pz = w_hh + ((size_t)ju + H) * H + k0;
        const float* pn = w_hh + ((size_t)ju + 2 * H) * H + k0;
        gemv_phase<false>(pr, pz, pn, hT4_in, k0 / 4, b, n,
                          accR, accZ, accNH);
    }

    // ---- reduce across KSPLIT waves, finish gates ----
    __shared__ float red[KSPLIT][COLS][4][64];
    red[kh][col][0][b] = accR;
    red[kh][col][1][b] = accZ;
    red[kh][col][2][b] = accNX;
    red[kh][col][3][b] = accNH;
    __syncthreads();

    if (tid < COLS * 64) {
        const int c  = tid >> 6;
        const int bb = tid & 63;
        float R = 0.f, Z = 0.f, NX = 0.f, NH = 0.f;
        #pragma unroll
        for (int k2 = 0; k2 < KSPLIT; ++k2) {
            R  += red[k2][c][0][bb];
            Z  += red[k2][c][1][bb];
            NX += red[k2][c][2][bb];
            NH += red[k2][c][3][bb];
        }
        const int j = blockIdx.x * COLS + c;
        const float r  = sigmoid_f(R + b_ih[j]     + b_hh[j]);
        const float zg = sigmoid_f(Z + b_ih[j + H] + b_hh[j + H]);
        const float n  = tanhf(NX + b_ih[j + 2 * H] + r * (NH + b_hh[j + 2 * H]));
        const float hprev = hT4_in[(((j >> 2) * 64 + bb) << 2) + (j & 3)];
        hT4_out[(((j >> 2) * 64 + bb) << 2) + (j & 3)] = (1.0f - zg) * n + zg * hprev;
    }
}

// Fused logits + argmax: one block per batch element, 512 threads = 8 waves.
__global__ __launch_bounds__(512) void out_kernel(
    const float* __restrict__ h2T4, const float* __restrict__ w_out,
    int* __restrict__ dec, int* __restrict__ out, int s, int max_len)
{
    __shared__ float hs[2048];
    __shared__ float lg[40];
    const int b    = blockIdx.x;
    const int tid  = threadIdx.x;
    const int wave = tid >> 6;    // 0..7
    const int lane = tid & 63;

    const float4* h4 = (const float4*)h2T4;
    ((float4*)hs)[tid] = h4[tid * 64 + b];    // 512 threads x 1 quad = 2048 f32
    __syncthreads();

    const float4* hs4 = (const float4*)hs;
    #pragma unroll
    for (int v = wave * 5; v < wave * 5 + 5; ++v) {
        const float4* w4 = (const float4*)(w_out + (size_t)v * 2048);
        float acc = 0.f;
        #pragma unroll
        for (int it = 0; it < 8; ++it) {
            const int k4 = it * 64 + lane;
            float4 wv = w4[k4];
            float4 hv = hs4[k4];
            acc = fmaf(wv.x, hv.x, acc);
            acc = fmaf(wv.y, hv.y, acc);
            acc = fmaf(wv.z, hv.z, acc);
            acc = fmaf(wv.w, hv.w, acc);
        }
        #pragma unroll
        for (int off = 32; off > 0; off >>= 1)
            acc += __shfl_down(acc, off, 64);
        if (lane == 0) lg[v] = acc;
    }
    __syncthreads();

    if (tid == 0) {
        float best = lg[0];
        int bi = 0;
        #pragma unroll
        for (int v = 1; v < 40; ++v) {
            const float val = lg[v];
            if (val > best) { best = val; bi = v; }
        }
        dec[b] = bi;
        out[b * max_len + s] = bi;
    }
}

extern "C" void kernel_launch(void* const* d_in, const int* in_sizes, int n_in,
                              void* d_out, int out_size, void* d_ws, size_t ws_size,
                              hipStream_t stream)
{
    const float* z         = (const float*)d_in[0];
    const float* emb       = (const float*)d_in[1];
    const float* fc_init_w = (const float*)d_in[2];
    const float* fc_init_b = (const float*)d_in[3];
    const float* fc_out_w  = (const float*)d_in[4];
    const float* w_ih0 = (const float*)d_in[5];
    const float* w_hh0 = (const float*)d_in[6];
    const float* b_ih0 = (const float*)d_in[7];
    const float* b_hh0 = (const float*)d_in[8];
    const float* w_ih1 = (const float*)d_in[9];
    const float* w_hh1 = (const float*)d_in[10];
    const float* b_ih1 = (const float*)d_in[11];
    const float* b_hh1 = (const float*)d_in[12];
    const float* w_ih2 = (const float*)d_in[13];
    const float* w_hh2 = (const float*)d_in[14];
    const float* b_ih2 = (const float*)d_in[15];
    const float* b_hh2 = (const float*)d_in[16];
    const int* start_tok = (const int*)d_in[18];

    // workspace layout (bytes)
    char* ws = (char*)d_ws;
    float* zT4    = (float*)(ws + 0);                                  // 128KB
    float* h0b[2] = { (float*)(ws + 131072), (float*)(ws + 262144) };  // 128KB each
    float* h1b[2] = { (float*)(ws + 393216), (float*)(ws + 655360) };  // 256KB each
    float* h2b[2] = { (float*)(ws + 917504), (float*)(ws + 1441792) }; // 512KB each
    int*   dec    = (int*)(ws + 1966080);

    int* out = (int*)d_out;
    const int max_len = out_size / BATCH;   // 64

    init_misc_kernel<<<32, 256, 0, stream>>>(z, zT4, dec, start_tok);
    init_h_kernel<<<896, 256, 0, stream>>>(zT4, fc_init_w, fc_init_b,
                                           h0b[0], h1b[0], h2b[0]);

    for (int s = 0; s < max_len; ++s) {
        const int pi = s & 1, po = pi ^ 1;
        // L0: COLS=2, KSPLIT=2 -> 256-thread blocks, 256 blocks
        gru4_kernel<32, 512, 2, 2, true><<<256, 256, 0, stream>>>(
            nullptr, emb, dec, h0b[pi], h0b[po], w_ih0, w_hh0, b_ih0, b_hh0);
        // L1: COLS=4, KSPLIT=2 -> 512-thread blocks, 256 blocks
        gru4_kernel<512, 1024, 4, 2, false><<<256, 512, 0, stream>>>(
            h0b[po], nullptr, nullptr, h1b[pi], h1b[po], w_ih1, w_hh1, b_ih1, b_hh1);
        // L2: COLS=4, KSPLIT=2 -> 512-thread blocks, 512 blocks
        gru4_kernel<1024, 2048, 4, 2, false><<<512, 512, 0, stream>>>(
            h1b[po], nullptr, nullptr, h2b[pi], h2b[po], w_ih2, w_hh2, b_ih2, b_hh2);
        // logits + argmax fused: 64 blocks (one per batch row), 512 threads
        out_kernel<<<64, 512, 0, stream>>>(h2b[po], fc_out_w, dec, out, s, max_len);
    }
}